// Round 17
// baseline (900.439 us; speedup 1.0000x reference)
//
#include <hip/hip_runtime.h>
#include <stdint.h>

#define H_ 64
#define W_ 64
#define D_ 256
#define U_ 512
#define KREC 1024           // 512 (h_up, w0) + 512 (h_left, w1)
#define CELL_ELT (32 * U_)  // elements per cell in hgrid

typedef __attribute__((ext_vector_type(8))) _Float16 half8;
typedef __attribute__((ext_vector_type(8))) unsigned short ushort8;
typedef __attribute__((ext_vector_type(4))) float f32x4;

__device__ __forceinline__ unsigned short f2h(float f) {
    _Float16 h = (_Float16)f;  // RNE
    return __builtin_bit_cast(unsigned short, h);
}

// Bank-conflict-free LDS offset: fold byte-addr bits [9:7] and row into bits [6:4].
__device__ __forceinline__ int swzo(int r, int o) {
    return o ^ (((r ^ (o >> 7)) & 7) << 4);
}

// wcT2[n][k] fp16: [w0; w1] transposed. n in [0,512), k in [0,1024).
__global__ void prep_w(const float* __restrict__ w0,
                       const float* __restrict__ w1,
                       unsigned short* __restrict__ wcT2) {
    int n = blockIdx.x;
    for (int k = threadIdx.x; k < KREC; k += blockDim.x) {
        float v = (k < U_) ? w0[(size_t)k * U_ + n] : w1[(size_t)(k - U_) * U_ + n];
        wcT2[(size_t)n * KREC + k] = f2h(v);
    }
}

// waxT[n][k] fp16, n in [0,512), k in [0,256)
__global__ void prep_waxT(const float* __restrict__ wax,
                          unsigned short* __restrict__ waxT) {
    int n = blockIdx.x;
    for (int k = threadIdx.x; k < D_; k += blockDim.x)
        waxT[(size_t)n * D_ + k] = f2h(wax[(size_t)k * U_ + n]);
}

// Z = x@wax + ba per cell, FRAGMENT-ORDERED fp16 (proven round 14):
// zfh[cell][gw 16][lane 64][16]; value idx = mt*8 + ntp*4 + rr maps to
// (row = mt*16 + (lane>>4)*4 + rr, col = gw*32 + ntp*16 + (lane&15)).
__global__ __launch_bounds__(256) void prep_z(
    const float* __restrict__ x,
    const unsigned short* __restrict__ waxT,
    const float* __restrict__ ba,
    unsigned short* __restrict__ zfh)
{
    __shared__ char xs[32 * 512];  // 16KB fp16, swizzled
    const int cell = blockIdx.x;
    const int t = threadIdx.x, lane = t & 63, wv = t >> 6;
    const int l15 = lane & 15, lh = lane >> 4;
    const int r = t >> 3, c8 = t & 7;

    {
        const float4* src = reinterpret_cast<const float4*>(
            x + (size_t)r * (H_ * W_ * D_) + (size_t)cell * D_ + c8 * 32);
        float4 f[8];
        #pragma unroll
        for (int q = 0; q < 8; ++q) f[q] = src[q];
        #pragma unroll
        for (int s = 0; s < 4; ++s) {
            float4 a = f[2 * s], b = f[2 * s + 1];
            ushort8 o;
            o[0] = f2h(a.x); o[1] = f2h(a.y); o[2] = f2h(a.z); o[3] = f2h(a.w);
            o[4] = f2h(b.x); o[5] = f2h(b.y); o[6] = f2h(b.z); o[7] = f2h(b.w);
            int ob = c8 * 64 + s * 16;
            *reinterpret_cast<ushort8*>(xs + r * 512 + swzo(r, ob)) = o;
        }
    }
    __syncthreads();

    f32x4 zero = {0.f, 0.f, 0.f, 0.f};
    f32x4 acc[2][8];
    #pragma unroll
    for (int m = 0; m < 2; ++m)
        #pragma unroll
        for (int n = 0; n < 8; ++n) acc[m][n] = zero;

    const char* ar0 = xs + l15 * 512;
    const char* ar1 = xs + (16 + l15) * 512;
    #pragma unroll
    for (int ks = 0; ks < 8; ++ks) {
        int oo = swzo(l15, ks * 64 + lh * 16);
        half8 af0 = *reinterpret_cast<const half8*>(ar0 + oo);
        half8 af1 = *reinterpret_cast<const half8*>(ar1 + oo);
        #pragma unroll
        for (int ntg = 0; ntg < 8; ++ntg) {
            int col = wv * 128 + ntg * 16 + l15;
            half8 bf = *reinterpret_cast<const half8*>(waxT + (size_t)col * D_ + ks * 32 + lh * 8);
            acc[0][ntg] = __builtin_amdgcn_mfma_f32_16x16x32_f16(af0, bf, acc[0][ntg], 0, 0, 0);
            acc[1][ntg] = __builtin_amdgcn_mfma_f32_16x16x32_f16(af1, bf, acc[1][ntg], 0, 0, 0);
        }
    }

    #pragma unroll
    for (int s = 0; s < 4; ++s) {
        unsigned short* dst = zfh + (((size_t)cell * 16 + wv * 4 + s) * 64 + lane) * 16;
        float bav0 = ba[wv * 128 + s * 32 + l15];
        float bav1 = ba[wv * 128 + s * 32 + 16 + l15];
        ushort8 oa, ob;
        #pragma unroll
        for (int rr = 0; rr < 4; ++rr) {
            oa[rr]     = f2h(acc[0][s * 2 + 0][rr] + bav0);
            oa[4 + rr] = f2h(acc[0][s * 2 + 1][rr] + bav1);
            ob[rr]     = f2h(acc[1][s * 2 + 0][rr] + bav0);
            ob[4 + rr] = f2h(acc[1][s * 2 + 1][rr] + bav1);
        }
        *reinterpret_cast<ushort8*>(dst)     = oa;
        *reinterpret_cast<ushort8*>(dst + 8) = ob;
    }
}

// Persistent recurrence (round-16 split-phase) + OPPORTUNISTIC ASYNC LEFT-STAGE:
// t0 checks the left flag concurrently with up-staging; if set (steady-state
// common case), left loads are issued into registers before MFMA-up and their
// latency hides under it. Blocking poll only on the rare not-ready hop.
__global__ __launch_bounds__(256, 1) void mdrnn_persistent(
    const unsigned short* __restrict__ wcT2,
    const unsigned short* __restrict__ zfh,
    unsigned short* __restrict__ hgrid,
    int* flags2,
    float* __restrict__ out)
{
    __shared__ char smb[32 * 2048];          // 64KB staging: 32 rows x (up | left)
    __shared__ unsigned long long heps64[32 * 32];  // 8KB epilogue transpose, LINEAR
    __shared__ int sLeftReady;
    unsigned short* heps16 = reinterpret_cast<unsigned short*>(heps64);

    const int j  = (int)blockIdx.x & 63;
    const int nc = (int)blockIdx.x >> 6;
    const int t = threadIdx.x, lane = t & 63, wv = t >> 6;
    const int l15 = lane & 15, lh = lane >> 4;
    const int r = t >> 3, c8 = t & 7;
    const int gw = nc * 4 + wv;
    const unsigned long long RDY2 = 0x0000000100000001ULL;

    // recurrent weights (128 N-cols x 1024 K) in registers: 256 VGPR
    half8 breg[2][32];
    {
        const unsigned short* wb = wcT2 + (size_t)(nc * 128 + wv * 32 + l15) * KREC + lh * 8;
        #pragma unroll
        for (int nt = 0; nt < 2; ++nt)
            #pragma unroll
            for (int ks = 0; ks < 32; ++ks)
                breg[nt][ks] = *reinterpret_cast<const half8*>(wb + (size_t)nt * 16 * KREC + ks * 32);
    }

    #pragma clang loop unroll(disable)
    for (int i = 0; i < H_; ++i) {
        const int cell = i * W_ + j;

        // Z prefetch (fp16, 32B): issued before any poll, lands during the wait
        const ushort8* zp = reinterpret_cast<const ushort8*>(
            zfh + (((size_t)cell * 16 + gw) * 64 + lane) * 16);
        ushort8 zv0 = zp[0], zv1 = zp[1];

        f32x4 zero = {0.f, 0.f, 0.f, 0.f};
        f32x4 acc00 = zero, acc01 = zero, acc10 = zero, acc11 = zero;
        const char* ar0 = smb + l15 * 2048;
        const char* ar1 = smb + (16 + l15) * 2048;

        const unsigned long long* fl = reinterpret_cast<const unsigned long long*>(
            flags2 + (size_t)(cell - 1) * 16);           // meaningful only when j>0
        const ushort8* ls = reinterpret_cast<const ushort8*>(
            hgrid + (size_t)(cell - 1) * CELL_ELT + (size_t)r * U_ + c8 * 64);

#define MSTEP(ks)                                                                                \
        {                                                                                        \
            int oo = swzo(l15, (ks) * 64 + lh * 16);                                             \
            half8 af0 = *reinterpret_cast<const half8*>(ar0 + oo);                               \
            half8 af1 = *reinterpret_cast<const half8*>(ar1 + oo);                               \
            acc00 = __builtin_amdgcn_mfma_f32_16x16x32_f16(af0, breg[0][(ks)], acc00, 0, 0, 0);  \
            acc01 = __builtin_amdgcn_mfma_f32_16x16x32_f16(af0, breg[1][(ks)], acc01, 0, 0, 0);  \
            acc10 = __builtin_amdgcn_mfma_f32_16x16x32_f16(af1, breg[0][(ks)], acc10, 0, 0, 0);  \
            acc11 = __builtin_amdgcn_mfma_f32_16x16x32_f16(af1, breg[1][(ks)], acc11, 0, 0, 0);  \
        }

        // ---------- PHASE U: poll up, stage up (+ t0's concurrent left check) ----------
        ushort8 ub[8];
        bool upAct = (i > 0);
        if (upAct) {
            const unsigned long long* fu = reinterpret_cast<const unsigned long long*>(
                flags2 + (size_t)(cell - W_) * 16);
            for (;;) {
                unsigned long long a = __hip_atomic_load(fu,     __ATOMIC_RELAXED, __HIP_MEMORY_SCOPE_AGENT);
                unsigned long long b = __hip_atomic_load(fu + 1, __ATOMIC_RELAXED, __HIP_MEMORY_SCOPE_AGENT);
                if (a == RDY2 && b == RDY2) break;
                __builtin_amdgcn_s_sleep(1);
            }
            asm volatile("" ::: "memory");
            const ushort8* us = reinterpret_cast<const ushort8*>(
                hgrid + (size_t)(cell - W_) * CELL_ELT + (size_t)r * U_ + c8 * 64);
            #pragma unroll
            for (int s = 0; s < 8; ++s) ub[s] = us[s];   // issue up loads
        }
        // t0: non-blocking left check — its RT pipelines with t0's up loads
        if (t == 0) {
            int lr = 0;
            if (j > 0) {
                unsigned long long a = __hip_atomic_load(fl,     __ATOMIC_RELAXED, __HIP_MEMORY_SCOPE_AGENT);
                unsigned long long b = __hip_atomic_load(fl + 1, __ATOMIC_RELAXED, __HIP_MEMORY_SCOPE_AGENT);
                lr = (a == RDY2 && b == RDY2) ? 1 : 0;
            }
            sLeftReady = lr;
        }
        if (upAct) {
            #pragma unroll
            for (int s = 0; s < 8; ++s) {
                int ob = c8 * 128 + s * 16;
                *reinterpret_cast<ushort8*>(smb + r * 2048 + swzo(r, ob)) = ub[s];
            }
        }
        __syncthreads();  // B1: up staged + sLeftReady visible (block-uniform)
        const bool lready = (j > 0) && (sLeftReady != 0);

        // async left-stage: issue loads into registers; they fly during MFMA-up
        ushort8 lb[8];
        if (lready) {
            #pragma unroll
            for (int s = 0; s < 8; ++s) lb[s] = ls[s];
        }

        if (upAct) {
            #pragma unroll
            for (int ks = 0; ks < 16; ++ks) MSTEP(ks)
        }

        // ---------- PHASE L ----------
        if (j > 0) {
            if (!lready) {   // rare: left not yet published when checked
                for (;;) {
                    unsigned long long a = __hip_atomic_load(fl,     __ATOMIC_RELAXED, __HIP_MEMORY_SCOPE_AGENT);
                    unsigned long long b = __hip_atomic_load(fl + 1, __ATOMIC_RELAXED, __HIP_MEMORY_SCOPE_AGENT);
                    if (a == RDY2 && b == RDY2) break;
                    __builtin_amdgcn_s_sleep(1);
                }
                asm volatile("" ::: "memory");
                #pragma unroll
                for (int s = 0; s < 8; ++s) lb[s] = ls[s];
            }
            #pragma unroll
            for (int s = 0; s < 8; ++s) {
                int ob = 1024 + c8 * 128 + s * 16;   // disjoint LDS region vs up
                *reinterpret_cast<ushort8*>(smb + r * 2048 + swzo(r, ob)) = lb[s];
            }
        }
        __syncthreads();  // B2: left staged before left-MFMA reads
        if (j > 0) {
            #pragma unroll
            for (int ks = 16; ks < 32; ++ks) MSTEP(ks)
        }
#undef MSTEP

        // epilogue phase 1: acc + Z(fp16->f32), tanh -> heps16 (LINEAR [32][128])
        const bool lastcell = (i == H_ - 1) && (j == W_ - 1);
        const int col0 = nc * 128 + wv * 32 + l15;
        const half8 hz0 = __builtin_bit_cast(half8, zv0);
        const half8 hz1 = __builtin_bit_cast(half8, zv1);
        #pragma unroll
        for (int mt = 0; mt < 2; ++mt) {
            f32x4 a0 = mt ? acc10 : acc00;
            f32x4 a1 = mt ? acc11 : acc01;
            half8 hz = mt ? hz1 : hz0;
            #pragma unroll
            for (int rr = 0; rr < 4; ++rr) {
                int row = mt * 16 + lh * 4 + rr;  // C/D: row=(lane>>4)*4+reg
                float v0 = fminf(fmaxf(a0[rr] + (float)hz[rr],     -15.f), 15.f);
                float v1 = fminf(fmaxf(a1[rr] + (float)hz[4 + rr], -15.f), 15.f);
                float e0 = __expf(2.f * v0), e1 = __expf(2.f * v1);
                float th0 = (e0 - 1.f) / (e0 + 1.f);
                float th1 = (e1 - 1.f) / (e1 + 1.f);
                heps16[row * 128 + wv * 32 + l15]      = f2h(th0);
                heps16[row * 128 + wv * 32 + 16 + l15] = f2h(th1);
                if (lastcell) {
                    out[(size_t)row * U_ + col0]      = th0;
                    out[(size_t)row * U_ + col0 + 16] = th1;
                }
            }
        }
        __syncthreads();  // B_t: transpose complete

        // epilogue phase 2: coalesced agent-scope stores (4 x 8B per thread)
        {
            const int erow = t >> 3, e = t & 7;
            unsigned long long* gq = reinterpret_cast<unsigned long long*>(
                hgrid + (size_t)cell * CELL_ELT + (size_t)erow * U_ + nc * 128);
            #pragma unroll
            for (int q = 0; q < 4; ++q) {
                unsigned long long v = heps64[erow * 32 + q * 8 + e];
                __hip_atomic_store(gq + q * 8 + e, v, __ATOMIC_RELAXED, __HIP_MEMORY_SCOPE_AGENT);
            }
        }

        // all agent stores acked at LLC before the barrier...
        asm volatile("s_waitcnt vmcnt(0)" ::: "memory");
        __syncthreads();  // B_f: also separates this iter's LDS reads from next staging
        // ...then publish this chunk: plain agent store, no RMW
        if (t == 0)
            __hip_atomic_store(&flags2[(size_t)cell * 16 + nc], 1,
                               __ATOMIC_RELAXED, __HIP_MEMORY_SCOPE_AGENT);
    }
}

extern "C" void kernel_launch(void* const* d_in, const int* in_sizes, int n_in,
                              void* d_out, int out_size, void* d_ws, size_t ws_size,
                              hipStream_t stream) {
    const float* x   = (const float*)d_in[0];
    const float* wax = (const float*)d_in[1];
    const float* w0  = (const float*)d_in[2];
    const float* w1  = (const float*)d_in[3];
    const float* ba  = (const float*)d_in[4];
    float* out = (float*)d_out;

    // ws layout: wcT2 1MiB | waxT 256KiB | flags2 256KiB | (pad to 2MiB) zfh 128MiB | hgrid 128MiB
    char* w = (char*)d_ws;
    unsigned short* wcT2   = (unsigned short*)(w);
    unsigned short* waxT   = (unsigned short*)(w + (1u << 20));
    int*            flags2 = (int*)(w + (1u << 20) + (256u << 10));
    unsigned short* zfh    = (unsigned short*)(w + (2u << 20));
    unsigned short* hgrid  = (unsigned short*)(w + (2u << 20) + ((size_t)128 << 20));

    (void)hipMemsetAsync(flags2, 0, (size_t)H_ * W_ * 16 * sizeof(int), stream);
    prep_w   <<<dim3(U_), dim3(256), 0, stream>>>(w0, w1, wcT2);
    prep_waxT<<<dim3(U_), dim3(256), 0, stream>>>(wax, waxT);
    prep_z   <<<dim3(H_ * W_), dim3(256), 0, stream>>>(x, waxT, ba, zfh);
    mdrnn_persistent<<<dim3(W_ * 4), dim3(256), 0, stream>>>(wcT2, zfh, hgrid, flags2, out);
}

// Round 19
// 883.588 us; speedup vs baseline: 1.0191x; 1.0191x over previous
//
#include <hip/hip_runtime.h>
#include <stdint.h>

#define H_ 64
#define W_ 64
#define D_ 256
#define U_ 512
#define KREC 1024           // 512 (h_up, w0) + 512 (h_left, w1)
#define CELL_ELT (32 * U_)  // elements per cell in hgrid

typedef __attribute__((ext_vector_type(8))) _Float16 half8;
typedef __attribute__((ext_vector_type(8))) unsigned short ushort8;
typedef __attribute__((ext_vector_type(4))) float f32x4;

__device__ __forceinline__ unsigned short f2h(float f) {
    _Float16 h = (_Float16)f;  // RNE
    return __builtin_bit_cast(unsigned short, h);
}

// Bank-conflict-free LDS offset: fold byte-addr bits [9:7] and row into bits [6:4].
__device__ __forceinline__ int swzo(int r, int o) {
    return o ^ (((r ^ (o >> 7)) & 7) << 4);
}

// wcT2[n][k] fp16: [w0; w1] transposed. n in [0,512), k in [0,1024).
__global__ void prep_w(const float* __restrict__ w0,
                       const float* __restrict__ w1,
                       unsigned short* __restrict__ wcT2) {
    int n = blockIdx.x;
    for (int k = threadIdx.x; k < KREC; k += blockDim.x) {
        float v = (k < U_) ? w0[(size_t)k * U_ + n] : w1[(size_t)(k - U_) * U_ + n];
        wcT2[(size_t)n * KREC + k] = f2h(v);
    }
}

// waxT[n][k] fp16, n in [0,512), k in [0,256)
__global__ void prep_waxT(const float* __restrict__ wax,
                          unsigned short* __restrict__ waxT) {
    int n = blockIdx.x;
    for (int k = threadIdx.x; k < D_; k += blockDim.x)
        waxT[(size_t)n * D_ + k] = f2h(wax[(size_t)k * U_ + n]);
}

// Z = x@wax + ba per cell, FRAGMENT-ORDERED fp16 (proven round 14):
// zfh[cell][gw 16][lane 64][16]; value idx = mt*8 + ntp*4 + rr maps to
// (row = mt*16 + (lane>>4)*4 + rr, col = gw*32 + ntp*16 + (lane&15)).
__global__ __launch_bounds__(256) void prep_z(
    const float* __restrict__ x,
    const unsigned short* __restrict__ waxT,
    const float* __restrict__ ba,
    unsigned short* __restrict__ zfh)
{
    __shared__ char xs[32 * 512];  // 16KB fp16, swizzled
    const int cell = blockIdx.x;
    const int t = threadIdx.x, lane = t & 63, wv = t >> 6;
    const int l15 = lane & 15, lh = lane >> 4;
    const int r = t >> 3, c8 = t & 7;

    {
        const float4* src = reinterpret_cast<const float4*>(
            x + (size_t)r * (H_ * W_ * D_) + (size_t)cell * D_ + c8 * 32);
        float4 f[8];
        #pragma unroll
        for (int q = 0; q < 8; ++q) f[q] = src[q];
        #pragma unroll
        for (int s = 0; s < 4; ++s) {
            float4 a = f[2 * s], b = f[2 * s + 1];
            ushort8 o;
            o[0] = f2h(a.x); o[1] = f2h(a.y); o[2] = f2h(a.z); o[3] = f2h(a.w);
            o[4] = f2h(b.x); o[5] = f2h(b.y); o[6] = f2h(b.z); o[7] = f2h(b.w);
            int ob = c8 * 64 + s * 16;
            *reinterpret_cast<ushort8*>(xs + r * 512 + swzo(r, ob)) = o;
        }
    }
    __syncthreads();

    f32x4 zero = {0.f, 0.f, 0.f, 0.f};
    f32x4 acc[2][8];
    #pragma unroll
    for (int m = 0; m < 2; ++m)
        #pragma unroll
        for (int n = 0; n < 8; ++n) acc[m][n] = zero;

    const char* ar0 = xs + l15 * 512;
    const char* ar1 = xs + (16 + l15) * 512;
    #pragma unroll
    for (int ks = 0; ks < 8; ++ks) {
        int oo = swzo(l15, ks * 64 + lh * 16);
        half8 af0 = *reinterpret_cast<const half8*>(ar0 + oo);
        half8 af1 = *reinterpret_cast<const half8*>(ar1 + oo);
        #pragma unroll
        for (int ntg = 0; ntg < 8; ++ntg) {
            int col = wv * 128 + ntg * 16 + l15;
            half8 bf = *reinterpret_cast<const half8*>(waxT + (size_t)col * D_ + ks * 32 + lh * 8);
            acc[0][ntg] = __builtin_amdgcn_mfma_f32_16x16x32_f16(af0, bf, acc[0][ntg], 0, 0, 0);
            acc[1][ntg] = __builtin_amdgcn_mfma_f32_16x16x32_f16(af1, bf, acc[1][ntg], 0, 0, 0);
        }
    }

    #pragma unroll
    for (int s = 0; s < 4; ++s) {
        unsigned short* dst = zfh + (((size_t)cell * 16 + wv * 4 + s) * 64 + lane) * 16;
        float bav0 = ba[wv * 128 + s * 32 + l15];
        float bav1 = ba[wv * 128 + s * 32 + 16 + l15];
        ushort8 oa, ob;
        #pragma unroll
        for (int rr = 0; rr < 4; ++rr) {
            oa[rr]     = f2h(acc[0][s * 2 + 0][rr] + bav0);
            oa[4 + rr] = f2h(acc[0][s * 2 + 1][rr] + bav1);
            ob[rr]     = f2h(acc[1][s * 2 + 0][rr] + bav0);
            ob[4 + rr] = f2h(acc[1][s * 2 + 1][rr] + bav1);
        }
        *reinterpret_cast<ushort8*>(dst)     = oa;
        *reinterpret_cast<ushort8*>(dst + 8) = ob;
    }
}

// Persistent recurrence (round-14 protocol), SPLIT-PHASE dependencies:
// phase U = {poll up, stage up, MFMA up}; phase L = {poll left, stage left, MFMA left}.
// Up-work hides under a late left flag. block b -> column j = b&63, chunk nc = b>>6
// (all 4 chunks of a column share blockIdx%8 -> same XCD).
__global__ __launch_bounds__(256, 1) void mdrnn_persistent(
    const unsigned short* __restrict__ wcT2,
    const unsigned short* __restrict__ zfh,
    unsigned short* __restrict__ hgrid,
    int* flags2,
    float* __restrict__ out)
{
    __shared__ char smb[32 * 2048];          // 64KB staging: 32 rows x (up | left)
    __shared__ unsigned long long heps64[32 * 32];  // 8KB epilogue transpose, LINEAR
    unsigned short* heps16 = reinterpret_cast<unsigned short*>(heps64);

    const int j  = (int)blockIdx.x & 63;
    const int nc = (int)blockIdx.x >> 6;
    const int t = threadIdx.x, lane = t & 63, wv = t >> 6;
    const int l15 = lane & 15, lh = lane >> 4;
    const int r = t >> 3, c8 = t & 7;
    const int gw = nc * 4 + wv;
    const unsigned long long RDY2 = 0x0000000100000001ULL;

    // recurrent weights (128 N-cols x 1024 K) in registers: 256 VGPR
    half8 breg[2][32];
    {
        const unsigned short* wb = wcT2 + (size_t)(nc * 128 + wv * 32 + l15) * KREC + lh * 8;
        #pragma unroll
        for (int nt = 0; nt < 2; ++nt)
            #pragma unroll
            for (int ks = 0; ks < 32; ++ks)
                breg[nt][ks] = *reinterpret_cast<const half8*>(wb + (size_t)nt * 16 * KREC + ks * 32);
    }

    #pragma clang loop unroll(disable)
    for (int i = 0; i < H_; ++i) {
        const int cell = i * W_ + j;

        // Z prefetch (fp16, 32B): issued before any poll, lands during the wait
        const ushort8* zp = reinterpret_cast<const ushort8*>(
            zfh + (((size_t)cell * 16 + gw) * 64 + lane) * 16);
        ushort8 zv0 = zp[0], zv1 = zp[1];

        f32x4 zero = {0.f, 0.f, 0.f, 0.f};
        f32x4 acc00 = zero, acc01 = zero, acc10 = zero, acc11 = zero;
        const char* ar0 = smb + l15 * 2048;
        const char* ar1 = smb + (16 + l15) * 2048;

#define MSTEP(ks)                                                                                \
        {                                                                                        \
            int oo = swzo(l15, (ks) * 64 + lh * 16);                                             \
            half8 af0 = *reinterpret_cast<const half8*>(ar0 + oo);                               \
            half8 af1 = *reinterpret_cast<const half8*>(ar1 + oo);                               \
            acc00 = __builtin_amdgcn_mfma_f32_16x16x32_f16(af0, breg[0][(ks)], acc00, 0, 0, 0);  \
            acc01 = __builtin_amdgcn_mfma_f32_16x16x32_f16(af0, breg[1][(ks)], acc01, 0, 0, 0);  \
            acc10 = __builtin_amdgcn_mfma_f32_16x16x32_f16(af1, breg[0][(ks)], acc10, 0, 0, 0);  \
            acc11 = __builtin_amdgcn_mfma_f32_16x16x32_f16(af1, breg[1][(ks)], acc11, 0, 0, 0);  \
        }

        // ---------- PHASE U: poll up, stage up, MFMA up ----------
        if (i > 0) {
            const unsigned long long* fu = reinterpret_cast<const unsigned long long*>(
                flags2 + (size_t)(cell - W_) * 16);
            for (;;) {
                unsigned long long a = __hip_atomic_load(fu,     __ATOMIC_RELAXED, __HIP_MEMORY_SCOPE_AGENT);
                unsigned long long b = __hip_atomic_load(fu + 1, __ATOMIC_RELAXED, __HIP_MEMORY_SCOPE_AGENT);
                if (a == RDY2 && b == RDY2) break;
                __builtin_amdgcn_s_sleep(1);
            }
            asm volatile("" ::: "memory");
            const ushort8* us = reinterpret_cast<const ushort8*>(
                hgrid + (size_t)(cell - W_) * CELL_ELT + (size_t)r * U_ + c8 * 64);
            ushort8 ub[8];
            #pragma unroll
            for (int s = 0; s < 8; ++s) ub[s] = us[s];
            #pragma unroll
            for (int s = 0; s < 8; ++s) {
                int ob = c8 * 128 + s * 16;
                *reinterpret_cast<ushort8*>(smb + r * 2048 + swzo(r, ob)) = ub[s];
            }
        }
        __syncthreads();  // B1: up staged before up-MFMA reads
        if (i > 0) {
            #pragma unroll
            for (int ks = 0; ks < 16; ++ks) MSTEP(ks)
        }

        // ---------- PHASE L: poll left, stage left, MFMA left ----------
        // (up-MFMA above executes while a late left flag is still in flight)
        if (j > 0) {
            const unsigned long long* fl = reinterpret_cast<const unsigned long long*>(
                flags2 + (size_t)(cell - 1) * 16);
            for (;;) {
                unsigned long long a = __hip_atomic_load(fl,     __ATOMIC_RELAXED, __HIP_MEMORY_SCOPE_AGENT);
                unsigned long long b = __hip_atomic_load(fl + 1, __ATOMIC_RELAXED, __HIP_MEMORY_SCOPE_AGENT);
                if (a == RDY2 && b == RDY2) break;
                __builtin_amdgcn_s_sleep(1);
            }
            asm volatile("" ::: "memory");
            const ushort8* ls = reinterpret_cast<const ushort8*>(
                hgrid + (size_t)(cell - 1) * CELL_ELT + (size_t)r * U_ + c8 * 64);
            ushort8 lb[8];
            #pragma unroll
            for (int s = 0; s < 8; ++s) lb[s] = ls[s];
            #pragma unroll
            for (int s = 0; s < 8; ++s) {
                int ob = 1024 + c8 * 128 + s * 16;   // disjoint LDS region vs up
                *reinterpret_cast<ushort8*>(smb + r * 2048 + swzo(r, ob)) = lb[s];
            }
        }
        __syncthreads();  // B2: left staged before left-MFMA reads
        if (j > 0) {
            #pragma unroll
            for (int ks = 16; ks < 32; ++ks) MSTEP(ks)
        }
#undef MSTEP

        // epilogue phase 1: acc + Z(fp16->f32), tanh -> heps16 (LINEAR [32][128])
        const bool lastcell = (i == H_ - 1) && (j == W_ - 1);
        const int col0 = nc * 128 + wv * 32 + l15;
        const half8 hz0 = __builtin_bit_cast(half8, zv0);
        const half8 hz1 = __builtin_bit_cast(half8, zv1);
        #pragma unroll
        for (int mt = 0; mt < 2; ++mt) {
            f32x4 a0 = mt ? acc10 : acc00;
            f32x4 a1 = mt ? acc11 : acc01;
            half8 hz = mt ? hz1 : hz0;
            #pragma unroll
            for (int rr = 0; rr < 4; ++rr) {
                int row = mt * 16 + lh * 4 + rr;  // C/D: row=(lane>>4)*4+reg
                float v0 = fminf(fmaxf(a0[rr] + (float)hz[rr],     -15.f), 15.f);
                float v1 = fminf(fmaxf(a1[rr] + (float)hz[4 + rr], -15.f), 15.f);
                float e0 = __expf(2.f * v0), e1 = __expf(2.f * v1);
                float th0 = (e0 - 1.f) / (e0 + 1.f);
                float th1 = (e1 - 1.f) / (e1 + 1.f);
                heps16[row * 128 + wv * 32 + l15]      = f2h(th0);
                heps16[row * 128 + wv * 32 + 16 + l15] = f2h(th1);
                if (lastcell) {
                    out[(size_t)row * U_ + col0]      = th0;
                    out[(size_t)row * U_ + col0 + 16] = th1;
                }
            }
        }
        __syncthreads();  // B_t: transpose complete

        // epilogue phase 2: coalesced agent-scope stores (4 x 8B per thread)
        {
            const int erow = t >> 3, e = t & 7;
            unsigned long long* gq = reinterpret_cast<unsigned long long*>(
                hgrid + (size_t)cell * CELL_ELT + (size_t)erow * U_ + nc * 128);
            #pragma unroll
            for (int q = 0; q < 4; ++q) {
                unsigned long long v = heps64[erow * 32 + q * 8 + e];
                __hip_atomic_store(gq + q * 8 + e, v, __ATOMIC_RELAXED, __HIP_MEMORY_SCOPE_AGENT);
            }
        }

        // all agent stores acked at LLC before the barrier...
        asm volatile("s_waitcnt vmcnt(0)" ::: "memory");
        __syncthreads();  // B_f: also separates this iter's LDS reads from next staging
        // ...then publish this chunk: plain agent store, no RMW
        if (t == 0)
            __hip_atomic_store(&flags2[(size_t)cell * 16 + nc], 1,
                               __ATOMIC_RELAXED, __HIP_MEMORY_SCOPE_AGENT);
    }
}

extern "C" void kernel_launch(void* const* d_in, const int* in_sizes, int n_in,
                              void* d_out, int out_size, void* d_ws, size_t ws_size,
                              hipStream_t stream) {
    const float* x   = (const float*)d_in[0];
    const float* wax = (const float*)d_in[1];
    const float* w0  = (const float*)d_in[2];
    const float* w1  = (const float*)d_in[3];
    const float* ba  = (const float*)d_in[4];
    float* out = (float*)d_out;

    // ws layout: wcT2 1MiB | waxT 256KiB | flags2 256KiB | (pad to 2MiB) zfh 128MiB | hgrid 128MiB
    char* w = (char*)d_ws;
    unsigned short* wcT2   = (unsigned short*)(w);
    unsigned short* waxT   = (unsigned short*)(w + (1u << 20));
    int*            flags2 = (int*)(w + (1u << 20) + (256u << 10));
    unsigned short* zfh    = (unsigned short*)(w + (2u << 20));
    unsigned short* hgrid  = (unsigned short*)(w + (2u << 20) + ((size_t)128 << 20));

    (void)hipMemsetAsync(flags2, 0, (size_t)H_ * W_ * 16 * sizeof(int), stream);
    prep_w   <<<dim3(U_), dim3(256), 0, stream>>>(w0, w1, wcT2);
    prep_waxT<<<dim3(U_), dim3(256), 0, stream>>>(wax, waxT);
    prep_z   <<<dim3(H_ * W_), dim3(256), 0, stream>>>(x, waxT, ba, zfh);
    mdrnn_persistent<<<dim3(W_ * 4), dim3(256), 0, stream>>>(wcT2, zfh, hgrid, flags2, out);
}